// Round 12
// baseline (107.884 us; speedup 1.0000x reference)
//
#include <hip/hip_runtime.h>
#include <hip/hip_bf16.h>
#include <cstdint>
#include <cstddef>

// Problem constants (fixed by reference)
#define NE 8      // experts
#define MEt 1024  // tokens per expert
#define KD 2048   // in features
#define ND 2048   // out features
#define NG 16     // K / G  (G = 128)

// Tile config
#define BM 256
#define BN 256
#define BK 128            // one scale-group per K-step
#define NKT (KD / BK)     // 16 K-steps
#define TILE_B (BM * BK)  // 32768 bytes per packed tile (A and B same)

typedef int   i32x4  __attribute__((ext_vector_type(4)));
typedef int   i32x16 __attribute__((ext_vector_type(16)));
typedef float f32x16 __attribute__((ext_vector_type(16)));

#define A_ROWS (NE * MEt)   // 8192
#define W_ROWS (NE * ND)    // 16384
#define A_BYTES ((size_t)A_ROWS * KD)   // 16 MiB packed
#define PP_BLOCKS 256
#define PP_ITERS  12        // 256 blocks * 12 iters * 8 rows = 24576 rows

__device__ __forceinline__ unsigned pack4(int x0, int x1, int x2, int x3) {
    return (unsigned)(x0 & 0xFF) | ((unsigned)(x1 & 0xFF) << 8) |
           ((unsigned)(x2 & 0xFF) << 16) | ((unsigned)x3 << 24);
}

__device__ __forceinline__ void gl_lds16(const void* g, void* l) {
    // async global->LDS, 16B/lane. LDS dest: uniform base + lane*16 (HW).
    // Global src: per-lane address.
    __builtin_amdgcn_global_load_lds(
        (const __attribute__((address_space(1))) void*)g,
        (__attribute__((address_space(3))) void*)l, 16, 0, 0);
}

// ---------------- prepack v8: persistent, counted-vmcnt pipelined, swizzled staging ----------------
// Packed layout (unchanged): tile(panel p, kt) contiguous 32KB:
//   addr = (p*NKT + kt)*TILE_B + kc*4096 + row_in_panel*16 + (k&15)
// 256 persistent blocks x 512 threads; 12 iterations x 8 rows (64KB) each.
// Pipeline per iteration (T4: loads in flight across barriers, NEVER vmcnt(0) mid-loop):
//   issue stage it+1 (8 glds/wave) -> vmcnt(8) [drains stage it only] -> s_barrier
//   -> 8x ds_read_b128 (conflict-free via source-baked XOR swizzle) -> lgkmcnt(0)
//   -> s_barrier (WAR: all reads done before next overwrite) -> pack + 128B-segment stores
__global__ __launch_bounds__(512)
void w4a8_prepack(const int* __restrict__ a_q, const int* __restrict__ w_q,
                  unsigned char* __restrict__ a8, unsigned char* __restrict__ w8)
{
    __shared__ __align__(16) unsigned char lbuf[2][65536];

    const int b    = blockIdx.x;
    const int tid  = threadIdx.x;
    const int wv   = tid >> 6;    // 0..7 : wave stages row wv of the 8-row group
    const int lane = tid & 63;
    const int kc   = lane >> 3;   // 0..7
    const int rr   = lane & 7;    // 0..7

    // issue one 8-row stage: wave wv loads row (R+wv), 8KB as 8x1KB chunks.
    // Source offset is granule-XOR-swizzled by row (m173 pattern): permutes 16B
    // granules within each 128B line -> coalescing preserved, LDS image swizzled.
    auto issue = [&](int it, int s) {
        int R = (b * PP_ITERS + it) * 8;
        const unsigned char* srcb;
        if (R < A_ROWS) srcb = (const unsigned char*)a_q + (size_t)(R + wv) * 8192;
        else            srcb = (const unsigned char*)w_q + (size_t)(R - A_ROWS + wv) * 8192;
        unsigned char* lb = &lbuf[s][wv * 8192];
#pragma unroll
        for (int i = 0; i < 8; ++i) {
            int off = (i * 1024 + lane * 16) ^ (wv << 4);
            gl_lds16(srcb + off, lb + i * 1024);
        }
    };

    issue(0, 0);

    for (int it = 0; it < PP_ITERS; ++it) {
        if (it + 1 < PP_ITERS) {
            issue(it + 1, (it + 1) & 1);
            asm volatile("s_waitcnt vmcnt(8)" ::: "memory");  // keep next stage in flight
        } else {
            asm volatile("s_waitcnt vmcnt(0)" ::: "memory");
        }
        __builtin_amdgcn_sched_barrier(0);
        __builtin_amdgcn_s_barrier();

        // phase 2: read this stage (swizzled addresses -> conflict-free b128)
        const unsigned char* lb = lbuf[it & 1];
        i32x4 v[2][4];
#pragma unroll
        for (int j = 0; j < 2; ++j) {
            int kt = j * 8 + wv;
#pragma unroll
            for (int q = 0; q < 4; ++q) {
                int addr = (rr * 8192 + kt * 512 + kc * 64 + q * 16) ^ (rr << 4);
                v[j][q] = *(const i32x4*)&lb[addr];
            }
        }
        asm volatile("s_waitcnt lgkmcnt(0)" ::: "memory");
        __builtin_amdgcn_sched_barrier(0);
        __builtin_amdgcn_s_barrier();   // all waves done reading before next overwrite

        // pack + store: 8 x 128B contiguous segments per wave-store
        int R = (b * PP_ITERS + it) * 8;
        unsigned char* dstb; int p, r0;
        if (R < A_ROWS) { dstb = a8; p = R >> 8; r0 = R & 255; }
        else { int Rw = R - A_ROWS; dstb = w8; p = Rw >> 8; r0 = Rw & 255; }
#pragma unroll
        for (int j = 0; j < 2; ++j) {
            int kt = j * 8 + wv;
            i32x4 pk;
            pk[0] = (int)pack4(v[j][0][0], v[j][0][1], v[j][0][2], v[j][0][3]);
            pk[1] = (int)pack4(v[j][1][0], v[j][1][1], v[j][1][2], v[j][1][3]);
            pk[2] = (int)pack4(v[j][2][0], v[j][2][1], v[j][2][2], v[j][2][3]);
            pk[3] = (int)pack4(v[j][3][0], v[j][3][1], v[j][3][2], v[j][3][3]);
            unsigned char* dp = dstb + (size_t)(p * NKT + kt) * TILE_B
                                     + (size_t)(kc * 4096 + (r0 + rr) * 16);
            *(i32x4*)dp = pk;
        }
    }
}

// ---------------- main GEMM: 256x256 tile, 8 waves, glds staging, conflict-free LDS ----------------
// (unchanged from R9/R11 — ~18us, near the 15.6us MFMA floor)
__device__ __forceinline__ void stage_tile(unsigned char* lds, const unsigned char* gtile,
                                           int wv, int lane) {
#pragma unroll
    for (int i = 0; i < 4; ++i) {
        int chunk = wv * 4 + i;
        gl_lds16(gtile + chunk * 1024 + lane * 16, lds + chunk * 1024);
    }
}

__global__ __launch_bounds__(512, 2)
void w4a8_gemm_pp(const unsigned char* __restrict__ a8,   // packed, tile-contiguous
                  const unsigned char* __restrict__ w8,
                  const float* __restrict__ per_tok,      // [M]
                  const float* __restrict__ per_chan,     // [E, N]
                  const float* __restrict__ wgs,          // [E, N, NG]
                  float* __restrict__ out)                // [M, N] fp32
{
    __shared__ __align__(16) unsigned char As[2][TILE_B];
    __shared__ __align__(16) unsigned char Bs[2][TILE_B];
    __shared__ float scs[NG][BN];

    // 256 blocks: XCD-chunked -> expert e on XCD e; 32 blocks per expert per XCD
    int bid = blockIdx.x;
    int b2  = (bid & 7) * 32 + (bid >> 3);
    const int e  = b2 >> 5;        // 0..7
    const int tm = (b2 >> 3) & 3;  // 0..3 (256-row panels)
    const int tn = b2 & 7;         // 0..7 (256-col panels)

    const int tid  = threadIdx.x;
    const int lane = tid & 63;
    const int wv   = tid >> 6;   // 0..7
    const int wm   = wv >> 2;    // 0..1  (row half: 128 rows)
    const int wn   = wv & 3;     // 0..3  (col quarter: 64 cols)
    const int lcol = lane & 31;
    const int lhi  = lane >> 5;

    const unsigned char* Ag = a8 + (size_t)((e * 4 + tm) * NKT) * TILE_B;
    const unsigned char* Wg = w8 + (size_t)((e * 8 + tn) * NKT) * TILE_B;

    f32x16 facc[4][2] = {};
    const i32x16 z16 = {};

    // prologue: stage tile 0 + all group scales
    stage_tile(As[0], Ag, wv, lane);
    stage_tile(Bs[0], Wg, wv, lane);
#pragma unroll
    for (int i = 0; i < 8; ++i) {
        int idx = tid + i * 512;
        int g = idx >> 8, n = idx & 255;
        scs[g][n] = wgs[((size_t)e * ND + tn * BN + n) * NG + g];
    }
    __syncthreads();

    int c = 0;
    for (int kt = 0; kt < NKT; ++kt) {
        if (kt + 1 < NKT) {
            stage_tile(As[c ^ 1], Ag + (kt + 1) * TILE_B, wv, lane);
            stage_tile(Bs[c ^ 1], Wg + (kt + 1) * TILE_B, wv, lane);
        }
        const unsigned char* Ac = As[c];
        const unsigned char* Bc = Bs[c];

        float sc0 = scs[kt][wn * 64 +  0 + lcol];
        float sc1 = scs[kt][wn * 64 + 32 + lcol];

        // B fragments for this wave's 64 columns: [ni][ks], lane-consecutive 16B reads
        i32x4 bfr[2][4];
#pragma unroll
        for (int ni = 0; ni < 2; ++ni)
#pragma unroll
            for (int ks = 0; ks < 4; ++ks) {
                int kch = ks * 2 + lhi;
                bfr[ni][ks] = *(const i32x4*)&Bc[kch * (256 * 16) + (wn * 64 + ni * 32 + lcol) * 16];
            }

#pragma unroll
        for (int mi = 0; mi < 4; ++mi) {
            i32x4 afr[4];
#pragma unroll
            for (int ks = 0; ks < 4; ++ks) {
                int kch = ks * 2 + lhi;
                afr[ks] = *(const i32x4*)&Ac[kch * (256 * 16) + (wm * 128 + mi * 32 + lcol) * 16];
            }
            i32x16 acc0, acc1;
            acc0 = __builtin_amdgcn_mfma_i32_32x32x32_i8(afr[0], bfr[0][0], z16, 0, 0, 0);
            acc1 = __builtin_amdgcn_mfma_i32_32x32x32_i8(afr[0], bfr[1][0], z16, 0, 0, 0);
            acc0 = __builtin_amdgcn_mfma_i32_32x32x32_i8(afr[1], bfr[0][1], acc0, 0, 0, 0);
            acc1 = __builtin_amdgcn_mfma_i32_32x32x32_i8(afr[1], bfr[1][1], acc1, 0, 0, 0);
            acc0 = __builtin_amdgcn_mfma_i32_32x32x32_i8(afr[2], bfr[0][2], acc0, 0, 0, 0);
            acc1 = __builtin_amdgcn_mfma_i32_32x32x32_i8(afr[2], bfr[1][2], acc1, 0, 0, 0);
            acc0 = __builtin_amdgcn_mfma_i32_32x32x32_i8(afr[3], bfr[0][3], acc0, 0, 0, 0);
            acc1 = __builtin_amdgcn_mfma_i32_32x32x32_i8(afr[3], bfr[1][3], acc1, 0, 0, 0);
#pragma unroll
            for (int i = 0; i < 16; ++i) {
                facc[mi][0][i] += (float)acc0[i] * sc0;
                facc[mi][1][i] += (float)acc1[i] * sc1;
            }
        }
        __syncthreads();
        c ^= 1;
    }

    // epilogue: per-token and per-channel scales, store fp32
    const float* ptok  = per_tok  + e * MEt + tm * BM;
    const float* pchan = per_chan + (size_t)e * ND + tn * BN;
    float* og = out + (size_t)(e * MEt + tm * BM) * ND + tn * BN;

#pragma unroll
    for (int mi = 0; mi < 4; ++mi) {
        int mb = wm * 128 + mi * 32;
#pragma unroll
        for (int ni = 0; ni < 2; ++ni) {
            int nn = wn * 64 + ni * 32 + lcol;
            float pc = pchan[nn];
#pragma unroll
            for (int rg = 0; rg < 16; ++rg) {
                int mr = mb + (rg & 3) + 8 * (rg >> 2) + 4 * lhi;
                float pt = ptok[mr];
                og[(size_t)mr * ND + nn] = facc[mi][ni][rg] * pt * pc;
            }
        }
    }
}

extern "C" void kernel_launch(void* const* d_in, const int* in_sizes, int n_in,
                              void* d_out, int out_size, void* d_ws, size_t ws_size,
                              hipStream_t stream) {
    const int*   a_q = (const int*)d_in[0];
    const int*   w_q = (const int*)d_in[1];
    const float* pt  = (const float*)d_in[2];
    const float* pc  = (const float*)d_in[3];
    const float* wg  = (const float*)d_in[4];
    float* out = (float*)d_out;

    unsigned char* a8 = (unsigned char*)d_ws;
    unsigned char* w8 = a8 + A_BYTES;

    // persistent prepack: 256 blocks x 512 threads x 12 iterations (8 rows each)
    w4a8_prepack<<<dim3(PP_BLOCKS), dim3(512), 0, stream>>>(a_q, w_q, a8, w8);
    // 8 experts * 4 m-tiles * 8 n-tiles = 256 blocks, 512 threads (8 waves)
    w4a8_gemm_pp<<<dim3(256), dim3(512), 0, stream>>>(a8, w8, pt, pc, wg, out);
}